// Round 10
// baseline (4258.994 us; speedup 1.0000x reference)
//
#include <hip/hip_runtime.h>
#include <hip/hip_bf16.h>
#include <math.h>

#define WS_ALIGN 256

__device__ __forceinline__ float elu_f(float x){ return x > 0.f ? x : expm1f(x); }

// ---------------- CSR build ----------------
__global__ void count_deg(const int* __restrict__ dst, int* __restrict__ deg, int E){
    int e = blockIdx.x*256 + threadIdx.x;
    if(e < E) atomicAdd(&deg[dst[e]], 1);
}

__global__ void scan1(const int* __restrict__ deg, int* __restrict__ off,
                      int* __restrict__ bsum, int n){
    __shared__ int s[256];
    int i = blockIdx.x*256 + threadIdx.x;
    int v = (i < n) ? deg[i] : 0;
    s[threadIdx.x] = v;
    __syncthreads();
    for(int d = 1; d < 256; d <<= 1){
        int t = (threadIdx.x >= d) ? s[threadIdx.x - d] : 0;
        __syncthreads();
        s[threadIdx.x] += t;
        __syncthreads();
    }
    if(i < n) off[i] = s[threadIdx.x] - v;          // block-local exclusive
    if(threadIdx.x == 255) bsum[blockIdx.x] = s[255];
}

__global__ void scan2(int* __restrict__ bsum, int nb){
    __shared__ int s[1024];
    int t = threadIdx.x;
    int v = (t < nb) ? bsum[t] : 0;
    s[t] = v;
    __syncthreads();
    for(int d = 1; d < 1024; d <<= 1){
        int x = (t >= d) ? s[t - d] : 0;
        __syncthreads();
        s[t] += x;
        __syncthreads();
    }
    if(t < nb) bsum[t] = s[t] - v;                  // exclusive block offsets
}

__global__ void scan3(int* __restrict__ off, const int* __restrict__ bsum, int n){
    int i = blockIdx.x*256 + threadIdx.x;
    if(i < n) off[i] += bsum[blockIdx.x];
}

__global__ void fill_csr(const int* __restrict__ src, const int* __restrict__ dst,
                         const int* __restrict__ off, int* __restrict__ fill,
                         int* __restrict__ csr, int E){
    int e = blockIdx.x*256 + threadIdx.x;
    if(e < E){
        int d = dst[e];
        int p = atomicAdd(&fill[d], 1);
        csr[off[d] + p] = src[e];
    }
}

// ---------------- aggregation (gather, mean) ----------------
// scalar variant (conv1: din=13)
template<int LANES>
__global__ void aggregate_s(const float* __restrict__ h, const int* __restrict__ off,
                            const int* __restrict__ deg, const int* __restrict__ csr,
                            float* __restrict__ agg, int M, int din, int inS, int outS){
    constexpr int NPB = 256 / LANES;
    int lane = threadIdx.x & (LANES - 1);
    int node = blockIdx.x*NPB + threadIdx.x / LANES;
    if(node >= M) return;
    int o = off[node], d = deg[node];
    bool act = lane < din;
    float acc = 0.f;
    for(int j = 0; j < d; j++){
        int s = csr[o + j];
        if(act) acc += h[(long)s*inS + lane];
    }
    if(act) agg[(long)node*outS + lane] = acc / fmaxf((float)d, 1.f);
}

// float4 variant: LANES = din/4 lanes per node; separate in/out row strides
template<int LANES>
__global__ void aggregate_v(const float* __restrict__ h, const int* __restrict__ off,
                            const int* __restrict__ deg, const int* __restrict__ csr,
                            float* __restrict__ agg, int M, int inS, int outS){
    constexpr int NPB = 256 / LANES;
    int lane = threadIdx.x & (LANES - 1);
    int node = blockIdx.x*NPB + threadIdx.x / LANES;
    if(node >= M) return;
    int o = off[node], d = deg[node];
    float4 acc = make_float4(0.f, 0.f, 0.f, 0.f);
    for(int j = 0; j < d; j++){
        int s = csr[o + j];
        float4 v = *reinterpret_cast<const float4*>(&h[(long)s*inS + lane*4]);
        acc.x += v.x; acc.y += v.y; acc.z += v.z; acc.w += v.w;
    }
    float inv = 1.f / fmaxf((float)d, 1.f);
    acc.x *= inv; acc.y *= inv; acc.z *= inv; acc.w *= inv;
    *reinterpret_cast<float4*>(&agg[(long)node*outS + lane*4]) = acc;
}

// ---------------- conv1 (K=13, N=128) ----------------
__global__ __launch_bounds__(256) void conv1_gemm(
        const float* __restrict__ agg, const float* __restrict__ x,
        const float* __restrict__ Wl, const float* __restrict__ Wr,
        const float* __restrict__ bl, float* __restrict__ out, int M){
    __shared__ float sWl[13*128];
    __shared__ float sWr[13*128];
    __shared__ float sb[128];
    int tid = threadIdx.x;
    for(int i = tid; i < 13*128; i += 256){ sWl[i] = Wl[i]; sWr[i] = Wr[i]; }
    if(tid < 128) sb[tid] = bl[tid];
    __syncthreads();
    int node = blockIdx.x*2 + (tid >> 7);
    int j = tid & 127;
    if(node >= M) return;
    float a = sb[j];
    #pragma unroll
    for(int k = 0; k < 13; k++){
        a = fmaf(agg[node*16 + k], sWl[k*128 + j], a);
        a = fmaf(x[node*13 + k],  sWr[k*128 + j], a);
    }
    out[(long)node*128 + j] = elu_f(a);
}

// ---------------- fused GEMM: C = [res +] elu(A1@W1 [+ A2@W2] + bias) ----------------
// BM=128, BN=N (full width -> each block owns its output rows; C may alias A1).
// 256 threads; per-thread 8 rows x N/16 cols in 4x4 sub-blocks (quadrant layout).
template<int N, bool DUAL, bool RESID>
__global__ __launch_bounds__(256) void gemm_fused(
        const float* __restrict__ A1, int lda1, const float* __restrict__ W1,
        const float* __restrict__ A2, int lda2, const float* __restrict__ W2,
        const float* __restrict__ bias, const float* __restrict__ res,
        float* __restrict__ C, int M, int K){
    constexpr int NQ = N / 64;                 // 4 for N=256, 2 for N=128
    __shared__ __align__(16) float As[16][132];
    __shared__ __align__(16) float Ws[16][N + 4];
    const int tid = threadIdx.x;
    const int m0 = blockIdx.x * 128;
    const int w = tid >> 6, l = tid & 63, tr = l >> 4, tc = l & 15;
    const int rg = w*4 + tr;   // 0..15 row-group

    float acc[2][NQ][4][4];
    #pragma unroll
    for(int a = 0; a < 2; a++)
    #pragma unroll
    for(int b = 0; b < NQ; b++)
    #pragma unroll
    for(int i = 0; i < 4; i++)
    #pragma unroll
    for(int j = 0; j < 4; j++) acc[a][b][i][j] = 0.f;

    const int nPhase = DUAL ? 2 : 1;
    for(int p = 0; p < nPhase; p++){
        const float* __restrict__ A = (p == 0) ? A1 : A2;
        const int lda = (p == 0) ? lda1 : lda2;
        const float* __restrict__ W = (p == 0) ? W1 : W2;
        for(int k0 = 0; k0 < K; k0 += 16){
            __syncthreads();
            // stage A tile (128 x 16, transposed into As[k][m])
            #pragma unroll
            for(int rep = 0; rep < 2; rep++){
                int idx = rep*256 + tid;
                int row = idx >> 2, c4 = idx & 3;
                int gm = m0 + row;
                float4 v = make_float4(0.f, 0.f, 0.f, 0.f);
                if(gm < M) v = *reinterpret_cast<const float4*>(&A[(long)gm*lda + k0 + c4*4]);
                As[c4*4 + 0][row] = v.x;
                As[c4*4 + 1][row] = v.y;
                As[c4*4 + 2][row] = v.z;
                As[c4*4 + 3][row] = v.w;
            }
            // stage W tile (16 x N)
            #pragma unroll
            for(int rep = 0; rep < (16*N/4)/256; rep++){
                int idx = rep*256 + tid;
                int kr = idx / (N/4), c4 = idx % (N/4);   // N compile-time -> shifts
                *reinterpret_cast<float4*>(&Ws[kr][c4*4]) =
                    *reinterpret_cast<const float4*>(&W[(long)(k0 + kr)*N + c4*4]);
            }
            __syncthreads();
            #pragma unroll
            for(int k = 0; k < 16; k++){
                float4 a0 = *reinterpret_cast<const float4*>(&As[k][rg*4]);
                float4 a1 = *reinterpret_cast<const float4*>(&As[k][64 + rg*4]);
                float av[2][4] = {{a0.x,a0.y,a0.z,a0.w},{a1.x,a1.y,a1.z,a1.w}};
                #pragma unroll
                for(int b = 0; b < NQ; b++){
                    float4 bb = *reinterpret_cast<const float4*>(&Ws[k][b*64 + tc*4]);
                    float bv[4] = {bb.x, bb.y, bb.z, bb.w};
                    #pragma unroll
                    for(int a = 0; a < 2; a++)
                    #pragma unroll
                    for(int i = 0; i < 4; i++)
                    #pragma unroll
                    for(int j = 0; j < 4; j++)
                        acc[a][b][i][j] = fmaf(av[a][i], bv[j], acc[a][b][i][j]);
                }
            }
        }
    }
    // epilogue (runs after the last barrier: all global A-reads of this block's
    // rows are complete, so C may alias A1)
    float bvv[NQ][4];
    #pragma unroll
    for(int b = 0; b < NQ; b++)
    #pragma unroll
    for(int j = 0; j < 4; j++) bvv[b][j] = bias[b*64 + tc*4 + j];

    #pragma unroll
    for(int a = 0; a < 2; a++){
        #pragma unroll
        for(int i = 0; i < 4; i++){
            int gm = m0 + a*64 + rg*4 + i;
            if(gm < M){
                #pragma unroll
                for(int b = 0; b < NQ; b++){
                    long base = (long)gm*N + b*64 + tc*4;
                    float v0 = elu_f(acc[a][b][i][0] + bvv[b][0]);
                    float v1 = elu_f(acc[a][b][i][1] + bvv[b][1]);
                    float v2 = elu_f(acc[a][b][i][2] + bvv[b][2]);
                    float v3 = elu_f(acc[a][b][i][3] + bvv[b][3]);
                    if(RESID){
                        float4 r = *reinterpret_cast<const float4*>(&res[base]);
                        v0 += r.x; v1 += r.y; v2 += r.z; v3 += r.w;
                    }
                    float4 o; o.x = v0; o.y = v1; o.z = v2; o.w = v3;
                    *reinterpret_cast<float4*>(&C[base]) = o;
                }
            }
        }
    }
}

// ---------------- pooling (batch is sorted) ----------------
__device__ __forceinline__ int lower_bound_i(const int* __restrict__ a, int n, int key){
    int lo = 0, hi = n;
    while(lo < hi){
        int mid = (lo + hi) >> 1;
        if(a[mid] < key) lo = mid + 1; else hi = mid;
    }
    return lo;
}

__global__ void pool_kernel(const float* __restrict__ h, const int* __restrict__ batch,
                            float* __restrict__ pooled, int M){
    int g = blockIdx.x, f = threadIdx.x;   // 128 threads
    int s = lower_bound_i(batch, M, g);
    int e = lower_bound_i(batch, M, g + 1);
    float acc = 0.f;
    for(int n = s; n < e; n++) acc += h[(long)n*128 + f];
    pooled[g*128 + f] = acc / fmaxf((float)(e - s), 1.f);
}

// ---------------- tail 1: BN -> fc3 -> elu (64 graphs per block, 32KB LDS) ----------
__global__ __launch_bounds__(256) void tail1_kernel(
        const float* __restrict__ pooled,
        const float* __restrict__ bng, const float* __restrict__ bnb,
        const float* __restrict__ bnrm, const float* __restrict__ bnrv,
        const float* __restrict__ fc3W, const float* __restrict__ fc3b,
        float* __restrict__ H, int G){
    __shared__ float P[64*128];
    int g0 = blockIdx.x * 64;
    int ng = G - g0; if(ng > 64) ng = 64; if(ng <= 0) return;
    int t = threadIdx.x;
    for(int i = t; i < ng*128; i += 256){
        int k = i & 127;
        P[i] = (pooled[g0*128 + i] - bnrm[k]) * (1.f / sqrtf(bnrv[k] + 1e-5f)) * bng[k] + bnb[k];
    }
    __syncthreads();
    for(int i = t; i < ng*64; i += 256){
        int gi = i >> 6, j = i & 63;
        float a = fc3b[j];
        for(int k = 0; k < 128; k++) a = fmaf(P[gi*128 + k], fc3W[k*64 + j], a);
        H[(g0 + gi)*64 + j] = elu_f(a);
    }
}

// ---------------- tail 2: out linear + L2 normalize ----------------
__global__ __launch_bounds__(128) void tail2_kernel(
        const float* __restrict__ H, const float* __restrict__ outW,
        const float* __restrict__ outb, float* __restrict__ out, int G){
    int t = threadIdx.x;
    if(t >= G) return;
    float o0 = outb[0], o1 = outb[1], o2 = outb[2];
    for(int j = 0; j < 64; j++){
        float h = H[t*64 + j];
        o0 = fmaf(h, outW[j*3 + 0], o0);
        o1 = fmaf(h, outW[j*3 + 1], o1);
        o2 = fmaf(h, outW[j*3 + 2], o2);
    }
    float nrm = sqrtf(o0*o0 + o1*o1 + o2*o2);
    float inv = 1.f / fmaxf(nrm, 1e-12f);
    out[t*3 + 0] = o0*inv;
    out[t*3 + 1] = o1*inv;
    out[t*3 + 2] = o2*inv;
}

// ---------------- launch ----------------
extern "C" void kernel_launch(void* const* d_in, const int* in_sizes, int n_in,
                              void* d_out, int out_size, void* d_ws, size_t ws_size,
                              hipStream_t stream){
    const int M = in_sizes[0];
    const int E = in_sizes[2] / 2;
    const int G = out_size / 3;

    const int*   batch = (const int*)d_in[0];
    const float* x     = (const float*)d_in[1];
    const int*   ei    = (const int*)d_in[2];
    const int*   srcE  = ei;
    const int*   dstE  = ei + E;

    const float* Wl[6]  = {(const float*)d_in[4],  (const float*)d_in[7],  (const float*)d_in[10],
                           (const float*)d_in[13], (const float*)d_in[16], (const float*)d_in[19]};
    const float* bl[6]  = {(const float*)d_in[5],  (const float*)d_in[8],  (const float*)d_in[11],
                           (const float*)d_in[14], (const float*)d_in[17], (const float*)d_in[20]};
    const float* Wr[6]  = {(const float*)d_in[6],  (const float*)d_in[9],  (const float*)d_in[12],
                           (const float*)d_in[15], (const float*)d_in[18], (const float*)d_in[21]};
    const float* fc1W = (const float*)d_in[22];
    const float* fc1b = (const float*)d_in[23];
    const float* fc2W = (const float*)d_in[24];
    const float* fc2b = (const float*)d_in[25];
    const float* bng  = (const float*)d_in[26];
    const float* bnb  = (const float*)d_in[27];
    const float* bnrm = (const float*)d_in[28];
    const float* bnrv = (const float*)d_in[29];
    const float* fc3W = (const float*)d_in[30];
    const float* fc3b = (const float*)d_in[31];
    const float* outW = (const float*)d_in[32];
    const float* outb = (const float*)d_in[33];

    char* ws = (char*)d_ws;
    size_t o = 0;
    auto alloc = [&](size_t bytes){
        size_t r = o;
        o = (o + bytes + (WS_ALIGN - 1)) & ~(size_t)(WS_ALIGN - 1);
        return r;
    };
    int*   deg    = (int*)(ws + alloc((size_t)M*4));
    int*   offp   = (int*)(ws + alloc((size_t)M*4));
    int*   fill   = (int*)(ws + alloc((size_t)M*4));
    int*   bsum   = (int*)(ws + alloc(1024*4));
    int*   csr    = (int*)(ws + alloc((size_t)E*4));
    float* B0     = (float*)(ws + alloc((size_t)M*256*4));
    float* B1     = (float*)(ws + alloc((size_t)M*256*4));
    float* pooled = (float*)(ws + alloc((size_t)G*128*4));
    float* Hbuf   = (float*)(ws + alloc((size_t)G*64*4));
    size_t need = o;
    (void)n_in;

    if(ws_size && need > ws_size){
        // insufficient scratch: emit zeros (clean diagnostic instead of OOB fault)
        hipMemsetAsync(d_out, 0, (size_t)out_size*4, stream);
        return;
    }

    hipMemsetAsync(deg,  0, (size_t)M*4, stream);
    hipMemsetAsync(fill, 0, (size_t)M*4, stream);

    int eb = (E + 255)/256;
    int nb = (M + 255)/256;
    count_deg<<<eb, 256, 0, stream>>>(dstE, deg, E);
    scan1<<<nb, 256, 0, stream>>>(deg, offp, bsum, M);
    scan2<<<1, 1024, 0, stream>>>(bsum, nb);
    scan3<<<nb, 256, 0, stream>>>(offp, bsum, M);
    fill_csr<<<eb, 256, 0, stream>>>(srcE, dstE, offp, fill, csr, E);

    const int gblk = (M + 127)/128;

    // conv1: 13 -> 128.  small agg (M x 16) aliases B1 (free until conv2 agg).
    float* agg1 = B1;
    aggregate_s<16><<<(M + 15)/16, 256, 0, stream>>>(x, offp, deg, csr, agg1, M, 13, 13, 16);
    conv1_gemm<<<(M + 1)/2, 256, 0, stream>>>(agg1, x, Wl[0], Wr[0], bl[0], B0, M);   // B0 stride 128

    // conv2: 128 -> 256.  agg(B0) -> B1 (stride 256), GEMM in-place into B1.
    aggregate_v<32><<<(M + 7)/8, 256, 0, stream>>>(B0, offp, deg, csr, B1, M, 128, 256);
    gemm_fused<256, true, false><<<gblk, 256, 0, stream>>>(B1, 256, Wl[1], B0, 128, Wr[1],
                                                           bl[1], nullptr, B1, M, 128);

    // conv3..6: 256 -> 256 with residual; ping-pong, GEMM in-place over agg buffer.
    float* hin = B1;
    float* hag = B0;
    for(int li = 2; li < 6; li++){
        aggregate_v<64><<<(M + 3)/4, 256, 0, stream>>>(hin, offp, deg, csr, hag, M, 256, 256);
        gemm_fused<256, true, true><<<gblk, 256, 0, stream>>>(hag, 256, Wl[li], hin, 256, Wr[li],
                                                              bl[li], hin, hag, M, 256);
        float* t = hin; hin = hag; hag = t;
    }
    // hin now holds conv6 output (B1)

    // fc1: residual, fully in-place on hin
    gemm_fused<256, false, true><<<gblk, 256, 0, stream>>>(hin, 256, fc1W, nullptr, 0, nullptr,
                                                           fc1b, hin, hin, M, 256);
    // fc2: 256 -> 128, into the other buffer (stride 128)
    gemm_fused<128, false, false><<<gblk, 256, 0, stream>>>(hin, 256, fc2W, nullptr, 0, nullptr,
                                                            fc2b, nullptr, hag, M, 256);

    pool_kernel<<<G, 128, 0, stream>>>(hag, batch, pooled, M);
    tail1_kernel<<<(G + 63)/64, 256, 0, stream>>>(pooled, bng, bnb, bnrm, bnrv,
                                                  fc3W, fc3b, Hbuf, G);
    tail2_kernel<<<1, 128, 0, stream>>>(Hbuf, outW, outb, (float*)d_out, G);
}

// Round 13
// 1586.359 us; speedup vs baseline: 2.6848x; 2.6848x over previous
//
#include <hip/hip_runtime.h>
#include <hip/hip_bf16.h>
#include <math.h>

#define WS_ALIGN 256

typedef _Float16 f16;
typedef _Float16 half8 __attribute__((ext_vector_type(8)));
typedef float f32x4 __attribute__((ext_vector_type(4)));

__device__ __forceinline__ float elu_f(float x){ return x > 0.f ? x : expm1f(x); }

// ---------------- CSR build ----------------
__global__ void count_deg(const int* __restrict__ dst, int* __restrict__ deg, int E){
    int e = blockIdx.x*256 + threadIdx.x;
    if(e < E) atomicAdd(&deg[dst[e]], 1);
}

__global__ void scan1(const int* __restrict__ deg, int* __restrict__ off,
                      int* __restrict__ bsum, int n){
    __shared__ int s[256];
    int i = blockIdx.x*256 + threadIdx.x;
    int v = (i < n) ? deg[i] : 0;
    s[threadIdx.x] = v;
    __syncthreads();
    for(int d = 1; d < 256; d <<= 1){
        int t = (threadIdx.x >= d) ? s[threadIdx.x - d] : 0;
        __syncthreads();
        s[threadIdx.x] += t;
        __syncthreads();
    }
    if(i < n) off[i] = s[threadIdx.x] - v;
    if(threadIdx.x == 255) bsum[blockIdx.x] = s[255];
}

__global__ void scan2(int* __restrict__ bsum, int nb){
    __shared__ int s[1024];
    int t = threadIdx.x;
    int v = (t < nb) ? bsum[t] : 0;
    s[t] = v;
    __syncthreads();
    for(int d = 1; d < 1024; d <<= 1){
        int x = (t >= d) ? s[t - d] : 0;
        __syncthreads();
        s[t] += x;
        __syncthreads();
    }
    if(t < nb) bsum[t] = s[t] - v;
}

__global__ void scan3(int* __restrict__ off, const int* __restrict__ bsum, int n){
    int i = blockIdx.x*256 + threadIdx.x;
    if(i < n) off[i] += bsum[blockIdx.x];
}

__global__ void fill_csr(const int* __restrict__ src, const int* __restrict__ dst,
                         const int* __restrict__ off, int* __restrict__ fill,
                         int* __restrict__ csr, int E){
    int e = blockIdx.x*256 + threadIdx.x;
    if(e < E){
        int d = dst[e];
        int p = atomicAdd(&fill[d], 1);
        csr[off[d] + p] = src[e];
    }
}

// ---------------- conv1 aggregation (fp32 x, din=13) ----------------
template<int LANES>
__global__ void aggregate_s(const float* __restrict__ h, const int* __restrict__ off,
                            const int* __restrict__ deg, const int* __restrict__ csr,
                            float* __restrict__ agg, int M, int din, int inS, int outS){
    constexpr int NPB = 256 / LANES;
    int lane = threadIdx.x & (LANES - 1);
    int node = blockIdx.x*NPB + threadIdx.x / LANES;
    if(node >= M) return;
    int o = off[node], d = deg[node];
    bool act = lane < din;
    float acc = 0.f;
    for(int j = 0; j < d; j++){
        int s = csr[o + j];
        if(act) acc += h[(long)s*inS + lane];
    }
    if(act) agg[(long)node*outS + lane] = acc / fmaxf((float)d, 1.f);
}

// ---------------- f16 aggregation: LANES lanes/node, 8 f16 per lane ------------
template<int LANES>
__global__ void aggregate_h(const f16* __restrict__ h, const int* __restrict__ off,
                            const int* __restrict__ deg, const int* __restrict__ csr,
                            f16* __restrict__ agg, int M, int inS, int outS){
    constexpr int NPB = 256 / LANES;
    int lane = threadIdx.x & (LANES - 1);
    int node = blockIdx.x*NPB + threadIdx.x / LANES;
    if(node >= M) return;
    int o = off[node], d = deg[node];
    float acc[8] = {0.f,0.f,0.f,0.f,0.f,0.f,0.f,0.f};
    for(int j = 0; j < d; j++){
        int s = csr[o + j];
        half8 v = *reinterpret_cast<const half8*>(&h[(long)s*inS + lane*8]);
        #pragma unroll
        for(int q = 0; q < 8; q++) acc[q] += (float)v[q];
    }
    float inv = 1.f / fmaxf((float)d, 1.f);
    half8 r;
    #pragma unroll
    for(int q = 0; q < 8; q++) r[q] = (f16)(acc[q]*inv);
    *reinterpret_cast<half8*>(&agg[(long)node*outS + lane*8]) = r;
}

// ---------------- weight prep: W[K][N] f32 -> Wt[N][K] f16 ----------------
__global__ void prep_wt(const float* __restrict__ W, f16* __restrict__ Wt, int K, int N){
    int i = blockIdx.x*256 + threadIdx.x;
    if(i >= K*N) return;
    int k = i / N, n = i - k*N;
    Wt[(long)n*K + k] = (f16)W[i];
}

// ---------------- conv1 (K=13, N=128), f16 out ----------------
__global__ __launch_bounds__(256) void conv1_gemm(
        const float* __restrict__ agg, const float* __restrict__ x,
        const float* __restrict__ Wl, const float* __restrict__ Wr,
        const float* __restrict__ bl, f16* __restrict__ out, int M){
    __shared__ float sWl[13*128];
    __shared__ float sWr[13*128];
    __shared__ float sb[128];
    int tid = threadIdx.x;
    for(int i = tid; i < 13*128; i += 256){ sWl[i] = Wl[i]; sWr[i] = Wr[i]; }
    if(tid < 128) sb[tid] = bl[tid];
    __syncthreads();
    int node = blockIdx.x*2 + (tid >> 7);
    int j = tid & 127;
    if(node >= M) return;
    float a = sb[j];
    #pragma unroll
    for(int k = 0; k < 13; k++){
        a = fmaf(agg[node*16 + k], sWl[k*128 + j], a);
        a = fmaf(x[node*13 + k],  sWr[k*128 + j], a);
    }
    out[(long)node*128 + j] = (f16)elu_f(a);
}

// ---------------- MFMA GEMM: C = [res +] elu(A1@W1 [+ A2@W2] + bias), all f16 I/O
// W?t is pre-transposed [N][K] f16.  BM=64 rows/block, BN=N (full width), 4 waves,
// wave w owns cols [w*N/4, (w+1)*N/4).  BK=64, mfma_f32_16x16x32_f16, fp32 accum.
// Fragment layout (gfx950): A: m=lane&15, k=(lane>>4)*8+i ; B: n=lane&15, same k;
// D: col=lane&15, row=(lane>>4)*4+reg  [m89-verified].
template<int N, bool DUAL, bool RESID>
__global__ __launch_bounds__(256) void gemm_mfma(
        const f16* __restrict__ A1, int lda1, const f16* __restrict__ W1t,
        const f16* __restrict__ A2, int lda2, const f16* __restrict__ W2t,
        const float* __restrict__ bias, const f16* __restrict__ res,
        f16* __restrict__ C, int M, int K){
    constexpr int WSL = N/4;       // wave col slice (64 or 32)
    constexpr int NF  = WSL/16;    // n-frags per wave (4 or 2)
    constexpr int KCSH = (N == 256) ? 8 : 7;
    __shared__ __align__(16) f16 Alds[8*64*8];    // [kc][row][8]  (kc = k/8 within BK=64)
    __shared__ __align__(16) f16 Wlds[8*N*8];     // [kc][n][8]
    const int tid = threadIdx.x;
    const int w   = tid >> 6;
    const int l   = tid & 63;
    const int lr  = l & 15;        // frag row (A) / col (B,D)
    const int kg  = l >> 4;        // k-group 0..3
    const long m0 = (long)blockIdx.x * 64;

    const f32x4 zero4 = {0.f, 0.f, 0.f, 0.f};
    f32x4 acc[4][NF];
    #pragma unroll
    for(int mi = 0; mi < 4; mi++)
        #pragma unroll
        for(int ni = 0; ni < NF; ni++) acc[mi][ni] = zero4;

    const int nPhase = DUAL ? 2 : 1;
    for(int p = 0; p < nPhase; p++){
        const f16* __restrict__ A  = (p == 0) ? A1 : A2;
        const int lda              = (p == 0) ? lda1 : lda2;
        const f16* __restrict__ Wt = (p == 0) ? W1t : W2t;
        for(int k0 = 0; k0 < K; k0 += 64){
            __syncthreads();
            // stage A tile: 64 rows x 64 f16 = 512 x 16B chunks
            #pragma unroll
            for(int it = 0; it < 2; it++){
                int kc = it*4 + (tid >> 6);
                int r  = tid & 63;
                long gm = m0 + r;
                uint4 v = make_uint4(0u, 0u, 0u, 0u);
                if(gm < M) v = *reinterpret_cast<const uint4*>(&A[gm*lda + k0 + kc*8]);
                *reinterpret_cast<uint4*>(&Alds[(kc*64 + r)*8]) = v;
            }
            // stage Wt tile: N rows x 64 f16
            #pragma unroll
            for(int it = 0; it < N*8/256; it++){
                int idx = it*256 + tid;
                int kc  = idx >> KCSH;
                int n   = idx & (N - 1);
                uint4 v = *reinterpret_cast<const uint4*>(&Wt[(long)n*K + k0 + kc*8]);
                *reinterpret_cast<uint4*>(&Wlds[(kc*N + n)*8]) = v;
            }
            __syncthreads();
            #pragma unroll
            for(int ks = 0; ks < 2; ks++){
                half8 af[4], bf[NF];
                #pragma unroll
                for(int mi = 0; mi < 4; mi++)
                    af[mi] = *reinterpret_cast<const half8*>(
                        &Alds[((ks*4 + kg)*64 + mi*16 + lr)*8]);
                #pragma unroll
                for(int ni = 0; ni < NF; ni++)
                    bf[ni] = *reinterpret_cast<const half8*>(
                        &Wlds[((ks*4 + kg)*N + w*WSL + ni*16 + lr)*8]);
                #pragma unroll
                for(int mi = 0; mi < 4; mi++)
                    #pragma unroll
                    for(int ni = 0; ni < NF; ni++)
                        acc[mi][ni] = __builtin_amdgcn_mfma_f32_16x16x32_f16(
                            af[mi], bf[ni], acc[mi][ni], 0, 0, 0);
            }
        }
    }
    // epilogue
    #pragma unroll
    for(int mi = 0; mi < 4; mi++){
        #pragma unroll
        for(int r = 0; r < 4; r++){
            long gm = m0 + mi*16 + kg*4 + r;
            if(gm < M){
                #pragma unroll
                for(int ni = 0; ni < NF; ni++){
                    int col = w*WSL + ni*16 + lr;
                    float v = acc[mi][ni][r] + bias[col];
                    v = elu_f(v);
                    if(RESID) v += (float)res[gm*N + col];
                    C[gm*N + col] = (f16)v;
                }
            }
        }
    }
}

// ---------------- pooling (batch sorted), f16 input ----------------
__device__ __forceinline__ int lower_bound_i(const int* __restrict__ a, int n, int key){
    int lo = 0, hi = n;
    while(lo < hi){
        int mid = (lo + hi) >> 1;
        if(a[mid] < key) lo = mid + 1; else hi = mid;
    }
    return lo;
}

__global__ void pool_kernel(const f16* __restrict__ h, const int* __restrict__ batch,
                            float* __restrict__ pooled, int M){
    int g = blockIdx.x, f = threadIdx.x;   // 128 threads
    int s = lower_bound_i(batch, M, g);
    int e = lower_bound_i(batch, M, g + 1);
    float acc = 0.f;
    for(int n = s; n < e; n++) acc += (float)h[(long)n*128 + f];
    pooled[g*128 + f] = acc / fmaxf((float)(e - s), 1.f);
}

// ---------------- tail 1: BN -> fc3 -> elu ----------------
__global__ __launch_bounds__(256) void tail1_kernel(
        const float* __restrict__ pooled,
        const float* __restrict__ bng, const float* __restrict__ bnb,
        const float* __restrict__ bnrm, const float* __restrict__ bnrv,
        const float* __restrict__ fc3W, const float* __restrict__ fc3b,
        float* __restrict__ H, int G){
    __shared__ float P[64*128];
    int g0 = blockIdx.x * 64;
    int ng = G - g0; if(ng > 64) ng = 64; if(ng <= 0) return;
    int t = threadIdx.x;
    for(int i = t; i < ng*128; i += 256){
        int k = i & 127;
        P[i] = (pooled[g0*128 + i] - bnrm[k]) * (1.f / sqrtf(bnrv[k] + 1e-5f)) * bng[k] + bnb[k];
    }
    __syncthreads();
    for(int i = t; i < ng*64; i += 256){
        int gi = i >> 6, j = i & 63;
        float a = fc3b[j];
        for(int k = 0; k < 128; k++) a = fmaf(P[gi*128 + k], fc3W[k*64 + j], a);
        H[(g0 + gi)*64 + j] = elu_f(a);
    }
}

// ---------------- tail 2: out linear + L2 normalize ----------------
__global__ __launch_bounds__(128) void tail2_kernel(
        const float* __restrict__ H, const float* __restrict__ outW,
        const float* __restrict__ outb, float* __restrict__ out, int G){
    int t = threadIdx.x;
    if(t >= G) return;
    float o0 = outb[0], o1 = outb[1], o2 = outb[2];
    for(int j = 0; j < 64; j++){
        float h = H[t*64 + j];
        o0 = fmaf(h, outW[j*3 + 0], o0);
        o1 = fmaf(h, outW[j*3 + 1], o1);
        o2 = fmaf(h, outW[j*3 + 2], o2);
    }
    float nrm = sqrtf(o0*o0 + o1*o1 + o2*o2);
    float inv = 1.f / fmaxf(nrm, 1e-12f);
    out[t*3 + 0] = o0*inv;
    out[t*3 + 1] = o1*inv;
    out[t*3 + 2] = o2*inv;
}

// ---------------- launch ----------------
extern "C" void kernel_launch(void* const* d_in, const int* in_sizes, int n_in,
                              void* d_out, int out_size, void* d_ws, size_t ws_size,
                              hipStream_t stream){
    const int M = in_sizes[0];
    const int E = in_sizes[2] / 2;
    const int G = out_size / 3;

    const int*   batch = (const int*)d_in[0];
    const float* x     = (const float*)d_in[1];
    const int*   ei    = (const int*)d_in[2];
    const int*   srcE  = ei;
    const int*   dstE  = ei + E;

    const float* Wl[6]  = {(const float*)d_in[4],  (const float*)d_in[7],  (const float*)d_in[10],
                           (const float*)d_in[13], (const float*)d_in[16], (const float*)d_in[19]};
    const float* bl[6]  = {(const float*)d_in[5],  (const float*)d_in[8],  (const float*)d_in[11],
                           (const float*)d_in[14], (const float*)d_in[17], (const float*)d_in[20]};
    const float* Wr[6]  = {(const float*)d_in[6],  (const float*)d_in[9],  (const float*)d_in[12],
                           (const float*)d_in[15], (const float*)d_in[18], (const float*)d_in[21]};
    const float* fc1W = (const float*)d_in[22];
    const float* fc1b = (const float*)d_in[23];
    const float* fc2W = (const float*)d_in[24];
    const float* fc2b = (const float*)d_in[25];
    const float* bng  = (const float*)d_in[26];
    const float* bnb  = (const float*)d_in[27];
    const float* bnrm = (const float*)d_in[28];
    const float* bnrv = (const float*)d_in[29];
    const float* fc3W = (const float*)d_in[30];
    const float* fc3b = (const float*)d_in[31];
    const float* outW = (const float*)d_in[32];
    const float* outb = (const float*)d_in[33];

    char* ws = (char*)d_ws;
    size_t o = 0;
    auto alloc = [&](size_t bytes){
        size_t r = o;
        o = (o + bytes + (WS_ALIGN - 1)) & ~(size_t)(WS_ALIGN - 1);
        return r;
    };
    int*   deg    = (int*)(ws + alloc((size_t)M*4));
    int*   offp   = (int*)(ws + alloc((size_t)M*4));
    int*   fill   = (int*)(ws + alloc((size_t)M*4));
    int*   bsum   = (int*)(ws + alloc(1024*4));
    int*   csr    = (int*)(ws + alloc((size_t)E*4));
    float* Sf     = (float*)(ws + alloc((size_t)M*16*4));       // conv1 agg (fp32)
    f16*   F0     = (f16*)(ws + alloc((size_t)M*256*2));
    f16*   F1     = (f16*)(ws + alloc((size_t)M*256*2));
    f16*   F2     = (f16*)(ws + alloc((size_t)M*256*2));
    // transposed f16 weights [N][K]
    f16*   wt_c2l = (f16*)(ws + alloc((size_t)256*128*2));
    f16*   wt_c2r = (f16*)(ws + alloc((size_t)256*128*2));
    f16*   wt_l[4]; f16* wt_r[4];
    for(int i = 0; i < 4; i++){
        wt_l[i] = (f16*)(ws + alloc((size_t)256*256*2));
        wt_r[i] = (f16*)(ws + alloc((size_t)256*256*2));
    }
    f16*   wt_fc1 = (f16*)(ws + alloc((size_t)256*256*2));
    f16*   wt_fc2 = (f16*)(ws + alloc((size_t)128*256*2));
    float* pooled = (float*)(ws + alloc((size_t)G*128*4));
    float* Hbuf   = (float*)(ws + alloc((size_t)G*64*4));
    size_t need = o;
    (void)n_in;

    if(ws_size && need > ws_size){
        hipMemsetAsync(d_out, 0, (size_t)out_size*4, stream);
        return;
    }

    hipMemsetAsync(deg,  0, (size_t)M*4, stream);
    hipMemsetAsync(fill, 0, (size_t)M*4, stream);

    int eb = (E + 255)/256;
    int nb = (M + 255)/256;
    count_deg<<<eb, 256, 0, stream>>>(dstE, deg, E);
    scan1<<<nb, 256, 0, stream>>>(deg, offp, bsum, M);
    scan2<<<1, 1024, 0, stream>>>(bsum, nb);
    scan3<<<nb, 256, 0, stream>>>(offp, bsum, M);
    fill_csr<<<eb, 256, 0, stream>>>(srcE, dstE, offp, fill, csr, E);

    // weight conversion (every call; graph-safe)
    prep_wt<<<(128*256 + 255)/256, 256, 0, stream>>>(Wl[1], wt_c2l, 128, 256);
    prep_wt<<<(128*256 + 255)/256, 256, 0, stream>>>(Wr[1], wt_c2r, 128, 256);
    for(int i = 0; i < 4; i++){
        prep_wt<<<(256*256 + 255)/256, 256, 0, stream>>>(Wl[2 + i], wt_l[i], 256, 256);
        prep_wt<<<(256*256 + 255)/256, 256, 0, stream>>>(Wr[2 + i], wt_r[i], 256, 256);
    }
    prep_wt<<<(256*256 + 255)/256, 256, 0, stream>>>(fc1W, wt_fc1, 256, 256);
    prep_wt<<<(256*128 + 255)/256, 256, 0, stream>>>(fc2W, wt_fc2, 256, 128);

    const int gm64 = (M + 63)/64;

    // conv1: 13 -> 128 (fp32 math, f16 out) -> F0 [M][128]
    aggregate_s<16><<<(M + 15)/16, 256, 0, stream>>>(x, offp, deg, csr, Sf, M, 13, 13, 16);
    conv1_gemm<<<(M + 1)/2, 256, 0, stream>>>(Sf, x, Wl[0], Wr[0], bl[0], F0, M);

    // conv2: 128 -> 256.  gather F0 -> F1 [M][128]; gemm -> F2 [M][256]
    aggregate_h<16><<<(M + 15)/16, 256, 0, stream>>>(F0, offp, deg, csr, F1, M, 128, 128);
    gemm_mfma<256, true, false><<<gm64, 256, 0, stream>>>(F1, 128, wt_c2l, F0, 128, wt_c2r,
                                                          bl[1], nullptr, F2, M, 128);

    // conv3..6: 256 -> 256 with residual.  hin alternates F2 -> F1 -> F2 -> F1 -> F2
    f16* hin = F2;
    f16* hout = F1;
    for(int li = 0; li < 4; li++){
        aggregate_h<32><<<(M + 7)/8, 256, 0, stream>>>(hin, offp, deg, csr, F0, M, 256, 256);
        gemm_mfma<256, true, true><<<gm64, 256, 0, stream>>>(F0, 256, wt_l[li], hin, 256, wt_r[li],
                                                             bl[2 + li], hin, hout, M, 256);
        f16* t = hin; hin = hout; hout = t;
    }
    // hin = conv6 output (F2)

    // fc1: residual -> F1
    gemm_mfma<256, false, true><<<gm64, 256, 0, stream>>>(hin, 256, wt_fc1, nullptr, 0, nullptr,
                                                          fc1b, hin, F1, M, 256);
    // fc2: 256 -> 128 -> F0 [M][128]
    gemm_mfma<128, false, false><<<gm64, 256, 0, stream>>>(F1, 256, wt_fc2, nullptr, 0, nullptr,
                                                           fc2b, nullptr, F0, M, 256);

    pool_kernel<<<G, 128, 0, stream>>>(F0, batch, pooled, M);
    tail1_kernel<<<(G + 63)/64, 256, 0, stream>>>(pooled, bng, bnb, bnrm, bnrv,
                                                  fc3W, fc3b, Hbuf, G);
    tail2_kernel<<<1, 128, 0, stream>>>(Hbuf, outW, outb, (float*)d_out, G);
}